// Round 9
// baseline (149.438 us; speedup 1.0000x reference)
//
#include <hip/hip_runtime.h>
#include <hip/hip_bf16.h>

#define B_ 128
#define L_ 196
#define D_ 1024

typedef __attribute__((ext_vector_type(8))) short short8v;
typedef __attribute__((ext_vector_type(4))) float f32x4;
typedef unsigned short ushort_t;

// d_ws layout (bytes). Max footprint 60,293,120 (proven size).
#define OFF_ATTBF   0UL          // 25088*1024*2 = 51,380,224
#define OFF_WBF     51380224UL   // 1024*1024*2  =  2,097,152
#define OFF_A2      53477376UL   // 128*2048*2   =    524,288   [x|h] bf16
#define OFF_W2      54001664UL   // 1024*2048*2  =  4,194,304   [Wi|Wh] bf16
#define OFF_SPART   53477376UL   // 16*25088*4   =  1,605,632   (aliases A2/W2: dead before score)
#define OFF_CPART   58195968UL   // 4*128*1024*4 =  2,097,152   c partials

__device__ inline unsigned short f2bf(float f) {
  unsigned int u = __float_as_uint(f);
  unsigned int r = (u + 0x7fffu + ((u >> 16) & 1u)) >> 16;
  return (unsigned short)r;
}

// ---------------- convert: fp32 -> bf16 staging buffers (r3-proven) ----------------
__global__ void convert_kernel(const float* __restrict__ att, const float* __restrict__ Wa,
                               const float* __restrict__ x,   const float* __restrict__ h,
                               const float* __restrict__ Wi,  const float* __restrict__ Wh,
                               ushort_t* __restrict__ att_bf, ushort_t* __restrict__ W_bf,
                               ushort_t* __restrict__ A2,     ushort_t* __restrict__ W2) {
  const int n0 = (B_*L_*D_)/4;
  const int n1 = (D_*D_)/4;
  const int n2 = (B_*D_)/4;
  const int total = n0 + n1 + 2*n2 + 2*n1;
  for (int idx = blockIdx.x*blockDim.x + threadIdx.x; idx < total;
       idx += gridDim.x*blockDim.x) {
    const float4* src; ushort_t* dst;
    int i = idx;
    if (i < n0)               { src = (const float4*)att + i; dst = att_bf + (size_t)i*4; }
    else if ((i -= n0) < n1)  { src = (const float4*)Wa  + i; dst = W_bf  + (size_t)i*4; }
    else if ((i -= n1) < n2)  { int b = i>>8, k4 = i&255; src = (const float4*)x  + i; dst = A2 + b*2048 + k4*4; }
    else if ((i -= n2) < n2)  { int b = i>>8, k4 = i&255; src = (const float4*)h  + i; dst = A2 + b*2048 + 1024 + k4*4; }
    else if ((i -= n2) < n1)  { int e = i>>8, k4 = i&255; src = (const float4*)Wi + i; dst = W2 + e*2048 + k4*4; }
    else { i -= n1;             int e = i>>8, k4 = i&255; src = (const float4*)Wh + i; dst = W2 + e*2048 + 1024 + k4*4; }
    float4 v = *src;
    ushort4 o; o.x = f2bf(v.x); o.y = f2bf(v.y); o.z = f2bf(v.z); o.w = f2bf(v.w);
    *(ushort4*)dst = o;
  }
}

// ---------------- c-matrix GEMM, split-K x4 (grid 32, r3-proven) ----------------
__device__ inline void stage_tile(const ushort_t* __restrict__ g, int row0, int Kld, int k0,
                                  ushort_t* ldst, int t) {
  #pragma unroll
  for (int it = 0; it < 4; ++it) {
    int linear = it*4096 + t*16;
    int r = linear >> 7;
    int c = (t & 7) ^ (r & 7);
    const ushort_t* src = g + (size_t)(row0 + r)*Kld + k0 + c*8;
    ushort_t* dst = ldst + ((it*4096 + ((t & 192) << 4)) >> 1);
    __builtin_amdgcn_global_load_lds((const __attribute__((address_space(1))) void*)src,
                                     (__attribute__((address_space(3))) void*)dst,
                                     16, 0, 0);
  }
}

__device__ inline short8v ldfrag(const ushort_t* tile, int row, int c) {
  int phys = c ^ (row & 7);
  return *(const short8v*)(tile + row*64 + phys*8);
}

__global__ __launch_bounds__(256) void gemm_c_kernel(
    const ushort_t* __restrict__ Amat, const ushort_t* __restrict__ Bmat,
    float* __restrict__ cpart) {
  __shared__ ushort_t lds[32768];
  int bid = blockIdx.x;
  int e0 = (bid & 7)*128;
  int kc = bid >> 3;               // 0..3, K-chunk of 512
  int kbeg = kc*512;
  const int Kld = 2048;
  int t = threadIdx.x, lane = t & 63, w = t >> 6;
  int wm = w >> 1, we = w & 1;
  int lrow = lane & 15;
  int lk = lane >> 4;

  f32x4 acc[4][4];
  #pragma unroll
  for (int i = 0; i < 4; ++i)
    #pragma unroll
    for (int j = 0; j < 4; ++j) acc[i][j] = (f32x4){0.f, 0.f, 0.f, 0.f};

  stage_tile(Amat, 0,  Kld, kbeg, lds, t);
  stage_tile(Bmat, e0, Kld, kbeg, lds + 8192, t);
  __syncthreads();

  const int nk = 8;                // 512 / 64
  for (int kt = 0; kt < nk; ++kt) {
    int cur = kt & 1;
    if (kt + 1 < nk) {
      stage_tile(Amat, 0,  Kld, kbeg + ((kt+1) << 6), lds + (cur^1)*16384, t);
      stage_tile(Bmat, e0, Kld, kbeg + ((kt+1) << 6), lds + (cur^1)*16384 + 8192, t);
    }
    const ushort_t* At = lds + cur*16384;
    const ushort_t* Bt = At + 8192;
    #pragma unroll
    for (int hh = 0; hh < 2; ++hh) {
      short8v af[4], bfv[4];
      #pragma unroll
      for (int i = 0; i < 4; ++i) af[i]  = ldfrag(At, wm*64 + i*16 + lrow, hh*4 + lk);
      #pragma unroll
      for (int j = 0; j < 4; ++j) bfv[j] = ldfrag(Bt, we*64 + j*16 + lrow, hh*4 + lk);
      #pragma unroll
      for (int i = 0; i < 4; ++i)
        #pragma unroll
        for (int j = 0; j < 4; ++j)
          acc[i][j] = __builtin_amdgcn_mfma_f32_16x16x32_bf16(af[i], bfv[j], acc[i][j], 0, 0, 0);
    }
    __syncthreads();
  }

  float* outc = cpart + (size_t)kc*131072;
  #pragma unroll
  for (int i = 0; i < 4; ++i) {
    int m = wm*64 + i*16 + lk*4;
    #pragma unroll
    for (int j = 0; j < 4; ++j) {
      int e = e0 + we*64 + j*16 + lrow;
      #pragma unroll
      for (int r = 0; r < 4; ++r)
        outc[(m + r)*1024 + e] = acc[i][j][r];
    }
  }
}

// ---------------- 128x128 score GEMM: r7 16x16 structure + PERSISTENT grid 768 ----------------
#define BARR()  __builtin_amdgcn_s_barrier()
#define VM0()   asm volatile("s_waitcnt vmcnt(0)" ::: "memory")

// stage one 128x64 bf16 tile (16KB): 4 x global_load_lds(16B)/thread (r7-proven).
__device__ inline void stageS(const ushort_t* __restrict__ g, int k0, ushort_t* ldsbase, int t) {
  #pragma unroll
  for (int it = 0; it < 4; ++it) {
    int linear = it*4096 + t*16;
    int r = linear >> 7;
    int c = ((linear >> 4) & 7) ^ (r & 7);
    const ushort_t* src = g + (size_t)r*1024 + k0 + c*8;
    ushort_t* dst = ldsbase + ((it*4096 + ((t & 192) << 4)) >> 1);
    __builtin_amdgcn_global_load_lds((const __attribute__((address_space(1))) void*)src,
                                     (__attribute__((address_space(3))) void*)dst,
                                     16, 0, 0);
  }
}

__global__ __launch_bounds__(256) void gemm_score_kernel(
    const ushort_t* __restrict__ Amat, const ushort_t* __restrict__ Bmat,
    const float* __restrict__ cpart,
    const float* __restrict__ ba, const float* __restrict__ bh, const float* __restrict__ bi,
    const float* __restrict__ wd,
    float* __restrict__ spart) {
  __shared__ ushort_t lds[16384];   // 32 KB: A[128][64]@0, B[128][64]@8192 (elems)
  __shared__ float c_lds[256];      // [2][128] per tile
  const int NT = 1568, GRID = 768;  // 768 % 8 == 0: tiles of one block share XCD class
  int t = (int)threadIdx.x, lane = t & 63, w = t >> 6;
  int wm = w >> 1, we = w & 1;
  int lrow = lane & 15, lk = lane >> 4;

  // loop-invariant ds_read base pointers (row&7 == lrow&7 for all frag rows)
  int lrow7 = lrow & 7;
  const ushort_t* pA0 = lds + (wm*64 + lrow)*64 + ((lk)     ^ lrow7)*8;
  const ushort_t* pA1 = lds + (wm*64 + lrow)*64 + (((4+lk)) ^ lrow7)*8;
  const ushort_t* pB0 = lds + 8192 + (we*64 + lrow)*64 + ((lk)     ^ lrow7)*8;
  const ushort_t* pB1 = lds + 8192 + (we*64 + lrow)*64 + (((4+lk)) ^ lrow7)*8;

  // stage first tile's K0
  {
    int tid0 = blockIdx.x;
    int swz0 = (tid0 & 7)*196 + (tid0 >> 3);
    stageS(Amat + (size_t)(swz0 >> 3)*131072, 0, lds, t);
    stageS(Bmat + (size_t)(swz0 & 7)*131072, 0, lds + 8192, t);
  }

  for (int tid = blockIdx.x; tid < NT; tid += GRID) {
    int swz = (tid & 7)*196 + (tid >> 3);
    int m_blk = swz >> 3, n_blk = swz & 7;
    int m0 = m_blk*128, e0 = n_blk*128;
    int bb0 = m0 / 196;

    __syncthreads();   // previous tile's epilogue done reading c_lds
    {
      int bb = bb0 + (t >> 7);
      int e  = e0 + (t & 127);
      float v = ba[e] + bh[e] + bi[e];
      if (bb < 128) {
        v += cpart[bb*1024 + e] + cpart[131072 + bb*1024 + e]
           + cpart[262144 + bb*1024 + e] + cpart[393216 + bb*1024 + e];
      }
      c_lds[t] = v;
    }

    const ushort_t* aG = Amat + (size_t)m0*1024;
    const ushort_t* bG = Bmat + (size_t)e0*1024;

    f32x4 acc[4][4];
    #pragma unroll
    for (int i = 0; i < 4; ++i)
      #pragma unroll
      for (int j = 0; j < 4; ++j) acc[i][j] = (f32x4){0.f, 0.f, 0.f, 0.f};

    for (int kt = 0; kt < 16; ++kt) {
      VM0();      // own staged loads landed
      BARR();     // all waves' loads landed -> tile kt complete
      __builtin_amdgcn_s_setprio(1);
      #pragma unroll
      for (int ks = 0; ks < 2; ++ks) {
        const ushort_t* pa = ks ? pA1 : pA0;
        const ushort_t* pb = ks ? pB1 : pB0;
        short8v af[4], bfv[4];
        #pragma unroll
        for (int i = 0; i < 4; ++i) af[i]  = *(const short8v*)(pa + i*1024);
        #pragma unroll
        for (int j = 0; j < 4; ++j) bfv[j] = *(const short8v*)(pb + j*1024);
        #pragma unroll
        for (int i = 0; i < 4; ++i)
          #pragma unroll
          for (int j = 0; j < 4; ++j)
            acc[i][j] = __builtin_amdgcn_mfma_f32_16x16x32_bf16(af[i], bfv[j], acc[i][j], 0, 0, 0);
      }
      __builtin_amdgcn_s_setprio(0);
      BARR();     // all waves' ds_reads of this K-tile retired -> overwrite safe
      if (kt < 15) {
        stageS(aG, (kt+1)*64, lds, t);
        stageS(bG, (kt+1)*64, lds + 8192, t);
      } else if (tid + GRID < NT) {
        // stage next tile's K0 now; its latency hides under the epilogue
        int nt2 = tid + GRID;
        int sz2 = (nt2 & 7)*196 + (nt2 >> 3);
        stageS(Amat + (size_t)(sz2 >> 3)*131072, 0, lds, t);
        stageS(Bmat + (size_t)(sz2 & 7)*131072, 0, lds + 8192, t);
      }
    }

    // epilogue: partial score = sum_e tanh(acc + c) * wd[e]; spart[p][m]
    int p = n_blk*2 + we;
    #pragma unroll
    for (int i = 0; i < 4; ++i) {
      int mbase = m0 + wm*64 + i*16 + lk*4;
      f32x4 ps;
      #pragma unroll
      for (int r = 0; r < 4; ++r) {
        int m = mbase + r;
        int bb = (int)((unsigned)m / 196u);
        float partial = 0.f;
        #pragma unroll
        for (int j = 0; j < 4; ++j) {
          int ee = we*64 + j*16 + lrow;
          float v = acc[i][j][r] + c_lds[(bb - bb0)*128 + ee];
          float ex = __expf(2.f*v);
          partial += (1.f - 2.f/(ex + 1.f)) * wd[e0 + ee];
        }
        partial += __shfl_xor(partial, 1);
        partial += __shfl_xor(partial, 2);
        partial += __shfl_xor(partial, 4);
        partial += __shfl_xor(partial, 8);
        ps[r] = partial;
      }
      if (lrow == 0) *(f32x4*)(spart + (size_t)p*25088 + mbase) = ps;
    }
  }
}

// ---------------- finalize: softmax over L, weighted sum of bf16 att (grid 512) ----------------
__global__ __launch_bounds__(256) void finalize_kernel(const ushort_t* __restrict__ att_bf,
                                                       const float* __restrict__ spart,
                                                       float* __restrict__ out) {
  int b  = blockIdx.x >> 2;
  int dq = blockIdx.x & 3;
  int t  = threadIdx.x;
  __shared__ float wls[L_];
  __shared__ float red[8];

  float s = -1e30f;
  if (t < L_) {
    int m = b*L_ + t;
    float sum = 0.f;
    #pragma unroll
    for (int p = 0; p < 16; ++p) sum += spart[p*25088 + m];
    s = sum;                       // b_d2d omitted: softmax shift-invariant
  }
  float mx = s;
  #pragma unroll
  for (int off = 1; off < 64; off <<= 1) mx = fmaxf(mx, __shfl_xor(mx, off));
  if ((t & 63) == 0) red[t >> 6] = mx;
  __syncthreads();
  mx = fmaxf(fmaxf(red[0], red[1]), fmaxf(red[2], red[3]));
  float pr = (t < L_) ? __expf(s - mx) : 0.f;
  float ssum = pr;
  #pragma unroll
  for (int off = 1; off < 64; off <<= 1) ssum += __shfl_xor(ssum, off);
  if ((t & 63) == 0) red[4 + (t >> 6)] = ssum;
  __syncthreads();
  float tot = red[4] + red[5] + red[6] + red[7];
  if (t < L_) wls[t] = pr / tot;
  __syncthreads();

  if (t < 128) {
    int d = dq*256 + t*2;
    const ushort_t* abase = att_bf + (size_t)b*L_*D_ + d;
    float a0 = 0.f, a1 = 0.f;
    #pragma unroll 4
    for (int l = 0; l < L_; ++l) {
      float wv = wls[l];
      unsigned int v = *(const unsigned int*)(abase + (size_t)l*D_);
      float lo = __uint_as_float(v << 16);
      float hif = __uint_as_float(v & 0xffff0000u);
      a0 += wv*lo; a1 += wv*hif;
    }
    float2 o; o.x = a0; o.y = a1;
    *(float2*)(out + (size_t)b*D_ + d) = o;
  }
}

extern "C" void kernel_launch(void* const* d_in, const int* in_sizes, int n_in,
                              void* d_out, int out_size, void* d_ws, size_t ws_size,
                              hipStream_t stream) {
  (void)in_sizes; (void)n_in; (void)out_size; (void)ws_size;
  const float* x   = (const float*)d_in[0];
  const float* att = (const float*)d_in[1];
  const float* h   = (const float*)d_in[2];
  const float* Wa  = (const float*)d_in[3];
  const float* ba  = (const float*)d_in[4];
  const float* Wh  = (const float*)d_in[5];
  const float* bh  = (const float*)d_in[6];
  const float* Wi  = (const float*)d_in[7];
  const float* bi  = (const float*)d_in[8];
  const float* wd  = (const float*)d_in[9];
  // d_in[10] = b_d2d: softmax shift-invariant, unused

  char* ws = (char*)d_ws;
  ushort_t* att_bf = (ushort_t*)(ws + OFF_ATTBF);
  ushort_t* W_bf   = (ushort_t*)(ws + OFF_WBF);
  ushort_t* A2     = (ushort_t*)(ws + OFF_A2);
  ushort_t* W2     = (ushort_t*)(ws + OFF_W2);
  float*    cpart  = (float*)(ws + OFF_CPART);
  float*    spart  = (float*)(ws + OFF_SPART);
  float*    out    = (float*)d_out;

  hipLaunchKernelGGL(convert_kernel, dim3(2048), dim3(256), 0, stream,
                     att, Wa, x, h, Wi, Wh, att_bf, W_bf, A2, W2);
  hipLaunchKernelGGL(gemm_c_kernel, dim3(32), dim3(256), 0, stream,
                     A2, W2, cpart);
  hipLaunchKernelGGL(gemm_score_kernel, dim3(768), dim3(256), 0, stream,
                     att_bf, W_bf, cpart, ba, bh, bi, wd, spart);
  hipLaunchKernelGGL(finalize_kernel, dim3(512), dim3(256), 0, stream,
                     att_bf, spart, out);
}

// Round 10
// 133.905 us; speedup vs baseline: 1.1160x; 1.1160x over previous
//
#include <hip/hip_runtime.h>
#include <hip/hip_bf16.h>

#define B_ 128
#define L_ 196
#define D_ 1024

typedef __attribute__((ext_vector_type(8))) short short8v;
typedef __attribute__((ext_vector_type(4))) float f32x4;
typedef unsigned short ushort_t;

// d_ws layout (bytes). Total ~10.5 MB (att_bf eliminated).
#define OFF_WBF     0UL          // 1024*1024*2  = 2,097,152
#define OFF_A2      2097152UL    // 128*2048*2   =   524,288   [x|h] bf16
#define OFF_W2      2621440UL    // 1024*2048*2  = 4,194,304   [Wi|Wh] bf16
#define OFF_SPART   6815744UL    // 16*25088*4   = 1,605,632
#define OFF_CPART   8421376UL    // 4*128*1024*4 = 2,097,152   (ends 10,518,528)

__device__ inline unsigned short f2bf(float f) {
  unsigned int u = __float_as_uint(f);
  unsigned int r = (u + 0x7fffu + ((u >> 16) & 1u)) >> 16;
  return (unsigned short)r;
}

__device__ inline unsigned int pk2(float a, float b) {
  unsigned int r;
  asm volatile("v_cvt_pk_bf16_f32 %0, %1, %2" : "=v"(r) : "v"(a), "v"(b));
  return r;
}

// ---------------- convert: Wa + x/h/Wi/Wh fp32 -> bf16 (att NOT converted) ----------------
__global__ void convert_kernel(const float* __restrict__ Wa,
                               const float* __restrict__ x,   const float* __restrict__ h,
                               const float* __restrict__ Wi,  const float* __restrict__ Wh,
                               ushort_t* __restrict__ W_bf,
                               ushort_t* __restrict__ A2,     ushort_t* __restrict__ W2) {
  const int n1 = (D_*D_)/4;      // 262,144
  const int n2 = (B_*D_)/4;      //  32,768
  const int total = n1 + 2*n2 + 2*n1;
  for (int idx = blockIdx.x*blockDim.x + threadIdx.x; idx < total;
       idx += gridDim.x*blockDim.x) {
    const float4* src; ushort_t* dst;
    int i = idx;
    if (i < n1)               { src = (const float4*)Wa  + i; dst = W_bf + (size_t)i*4; }
    else if ((i -= n1) < n2)  { int b = i>>8, k4 = i&255; src = (const float4*)x  + i; dst = A2 + b*2048 + k4*4; }
    else if ((i -= n2) < n2)  { int b = i>>8, k4 = i&255; src = (const float4*)h  + i; dst = A2 + b*2048 + 1024 + k4*4; }
    else if ((i -= n2) < n1)  { int e = i>>8, k4 = i&255; src = (const float4*)Wi + i; dst = W2 + e*2048 + k4*4; }
    else { i -= n1;             int e = i>>8, k4 = i&255; src = (const float4*)Wh + i; dst = W2 + e*2048 + 1024 + k4*4; }
    float4 v = *src;
    ushort4 o; o.x = f2bf(v.x); o.y = f2bf(v.y); o.z = f2bf(v.z); o.w = f2bf(v.w);
    *(ushort4*)dst = o;
  }
}

// ---------------- c-matrix GEMM, split-K x4 (grid 32, r3-proven) ----------------
__device__ inline void stage_tile(const ushort_t* __restrict__ g, int row0, int Kld, int k0,
                                  ushort_t* ldst, int t) {
  #pragma unroll
  for (int it = 0; it < 4; ++it) {
    int linear = it*4096 + t*16;
    int r = linear >> 7;
    int c = (t & 7) ^ (r & 7);
    const ushort_t* src = g + (size_t)(row0 + r)*Kld + k0 + c*8;
    ushort_t* dst = ldst + ((it*4096 + ((t & 192) << 4)) >> 1);
    __builtin_amdgcn_global_load_lds((const __attribute__((address_space(1))) void*)src,
                                     (__attribute__((address_space(3))) void*)dst,
                                     16, 0, 0);
  }
}

__device__ inline short8v ldfrag(const ushort_t* tile, int row, int c) {
  int phys = c ^ (row & 7);
  return *(const short8v*)(tile + row*64 + phys*8);
}

__global__ __launch_bounds__(256) void gemm_c_kernel(
    const ushort_t* __restrict__ Amat, const ushort_t* __restrict__ Bmat,
    float* __restrict__ cpart) {
  __shared__ ushort_t lds[32768];
  int bid = blockIdx.x;
  int e0 = (bid & 7)*128;
  int kc = bid >> 3;
  int kbeg = kc*512;
  const int Kld = 2048;
  int t = threadIdx.x, lane = t & 63, w = t >> 6;
  int wm = w >> 1, we = w & 1;
  int lrow = lane & 15;
  int lk = lane >> 4;

  f32x4 acc[4][4];
  #pragma unroll
  for (int i = 0; i < 4; ++i)
    #pragma unroll
    for (int j = 0; j < 4; ++j) acc[i][j] = (f32x4){0.f, 0.f, 0.f, 0.f};

  stage_tile(Amat, 0,  Kld, kbeg, lds, t);
  stage_tile(Bmat, e0, Kld, kbeg, lds + 8192, t);
  __syncthreads();

  const int nk = 8;
  for (int kt = 0; kt < nk; ++kt) {
    int cur = kt & 1;
    if (kt + 1 < nk) {
      stage_tile(Amat, 0,  Kld, kbeg + ((kt+1) << 6), lds + (cur^1)*16384, t);
      stage_tile(Bmat, e0, Kld, kbeg + ((kt+1) << 6), lds + (cur^1)*16384 + 8192, t);
    }
    const ushort_t* At = lds + cur*16384;
    const ushort_t* Bt = At + 8192;
    #pragma unroll
    for (int hh = 0; hh < 2; ++hh) {
      short8v af[4], bfv[4];
      #pragma unroll
      for (int i = 0; i < 4; ++i) af[i]  = ldfrag(At, wm*64 + i*16 + lrow, hh*4 + lk);
      #pragma unroll
      for (int j = 0; j < 4; ++j) bfv[j] = ldfrag(Bt, we*64 + j*16 + lrow, hh*4 + lk);
      #pragma unroll
      for (int i = 0; i < 4; ++i)
        #pragma unroll
        for (int j = 0; j < 4; ++j)
          acc[i][j] = __builtin_amdgcn_mfma_f32_16x16x32_bf16(af[i], bfv[j], acc[i][j], 0, 0, 0);
    }
    __syncthreads();
  }

  float* outc = cpart + (size_t)kc*131072;
  #pragma unroll
  for (int i = 0; i < 4; ++i) {
    int m = wm*64 + i*16 + lk*4;
    #pragma unroll
    for (int j = 0; j < 4; ++j) {
      int e = e0 + we*64 + j*16 + lrow;
      #pragma unroll
      for (int r = 0; r < 4; ++r)
        outc[(m + r)*1024 + e] = acc[i][j][r];
    }
  }
}

// ---------------- 128x128 score GEMM: r7 structure + FUSED fp32-att A-path ----------------
#define BARR()  __builtin_amdgcn_s_barrier()
#define VM0()   asm volatile("s_waitcnt vmcnt(0)" ::: "memory")
#define VM8()   asm volatile("s_waitcnt vmcnt(8)" ::: "memory")
#define VM4()   asm volatile("s_waitcnt vmcnt(4)" ::: "memory")
#define LGKM0() asm volatile("s_waitcnt lgkmcnt(0)" ::: "memory")

// stage one 128x64 bf16 tile (16KB): 4 x global_load_lds(16B)/thread (B-side, r7-proven).
__device__ inline void stageS(const ushort_t* __restrict__ g, int k0, ushort_t* ldsbase, int t) {
  #pragma unroll
  for (int it = 0; it < 4; ++it) {
    int linear = it*4096 + t*16;
    int r = linear >> 7;
    int c = ((linear >> 4) & 7) ^ (r & 7);
    const ushort_t* src = g + (size_t)r*1024 + k0 + c*8;
    ushort_t* dst = ldsbase + ((it*4096 + ((t & 192) << 4)) >> 1);
    __builtin_amdgcn_global_load_lds((const __attribute__((address_space(1))) void*)src,
                                     (__attribute__((address_space(3))) void*)dst,
                                     16, 0, 0);
  }
}

__global__ __launch_bounds__(256) void gemm_score_kernel(
    const float* __restrict__ attf, const ushort_t* __restrict__ Bmat,
    const float* __restrict__ cpart,
    const float* __restrict__ ba, const float* __restrict__ bh, const float* __restrict__ bi,
    const float* __restrict__ wd,
    float* __restrict__ spart) {
  __shared__ ushort_t lds[16384];   // 32 KB: A[128][64]@0, B[128][64]@8192 (elems)
  __shared__ float c_lds[256];
  int bid = blockIdx.x;
  int swz = (bid & 7)*196 + (bid >> 3);    // 1568 % 8 == 0 -> bijective XCD swizzle
  int m_blk = swz >> 3, n_blk = swz & 7;
  int m0 = m_blk*128, e0 = n_blk*128;
  int t = (int)threadIdx.x, lane = t & 63, w = t >> 6;
  int wm = w >> 1, we = w & 1;
  int lrow = lane & 15, lk = lane >> 4;

  // c_lds = biases + sum of 4 K-partials
  int bb0 = m0 / 196;
  {
    int bb = bb0 + (t >> 7);
    int e  = e0 + (t & 127);
    float v = ba[e] + bh[e] + bi[e];
    if (bb < 128) {
      v += cpart[bb*1024 + e] + cpart[131072 + bb*1024 + e]
         + cpart[262144 + bb*1024 + e] + cpart[393216 + bb*1024 + e];
    }
    c_lds[t] = v;
  }

  const ushort_t* bG = Bmat + (size_t)e0*1024;

  // A-path per-thread coords: rows ar+32*it, logical chunk ac (8 bf16 = 8 fp32)
  int ar = t >> 3, ac = t & 7;
  const float* ald = attf + (size_t)(m0 + ar)*1024 + ac*8;
  ushort_t* awr = lds + ar*64 + ((ac ^ (ar & 7))*8);   // 16B-aligned

  // loop-invariant ds_read base pointers (row&7 == lrow&7 for all frag rows)
  int lrow7 = lrow & 7;
  const ushort_t* pA0 = lds + (wm*64 + lrow)*64 + ((lk)     ^ lrow7)*8;
  const ushort_t* pA1 = lds + (wm*64 + lrow)*64 + (((4+lk)) ^ lrow7)*8;
  const ushort_t* pB0 = lds + 8192 + (we*64 + lrow)*64 + ((lk)     ^ lrow7)*8;
  const ushort_t* pB1 = lds + 8192 + (we*64 + lrow)*64 + (((4+lk)) ^ lrow7)*8;

  f32x4 acc[4][4];
  #pragma unroll
  for (int i = 0; i < 4; ++i)
    #pragma unroll
    for (int j = 0; j < 4; ++j) acc[i][j] = (f32x4){0.f, 0.f, 0.f, 0.f};

  // prologue: B(0) via global_load_lds; A(0) fp32 -> regs; cvt
  stageS(bG, 0, lds + 8192, t);
  float4 La[4][2];
  #pragma unroll
  for (int it = 0; it < 4; ++it) {
    La[it][0] = *(const float4*)(ald + (size_t)it*32768);
    La[it][1] = *(const float4*)(ald + (size_t)it*32768 + 4);
  }
  VM0();
  uint4 Aw[4];
  #pragma unroll
  for (int it = 0; it < 4; ++it) {
    Aw[it].x = pk2(La[it][0].x, La[it][0].y);
    Aw[it].y = pk2(La[it][0].z, La[it][0].w);
    Aw[it].z = pk2(La[it][1].x, La[it][1].y);
    Aw[it].w = pk2(La[it][1].z, La[it][1].w);
  }

  for (int kt = 0; kt < 16; ++kt) {
    // write A(kt) to LDS (region free: all A-reads of kt-1 retired before BARR2(kt-1))
    #pragma unroll
    for (int it = 0; it < 4; ++it)
      *reinterpret_cast<uint4*>(awr + it*2048) = Aw[it];
    if (kt < 15) {
      // issue A(kt+1) reg loads; latency covered by the MFMA region
      #pragma unroll
      for (int it = 0; it < 4; ++it) {
        La[it][0] = *(const float4*)(ald + (size_t)it*32768 + (kt+1)*64);
        La[it][1] = *(const float4*)(ald + (size_t)it*32768 + (kt+1)*64 + 4);
      }
      VM8();     // 4 B-loads (older) + 8 A-loads: drains exactly B(kt)
    } else {
      VM0();     // last tile: drain B(15)
    }
    LGKM0();     // ds_writes of A(kt) visible
    BARR();      // all waves: A(kt)+B(kt) complete in LDS
    __builtin_amdgcn_s_setprio(1);
    #pragma unroll
    for (int ks = 0; ks < 2; ++ks) {
      const ushort_t* pa = ks ? pA1 : pA0;
      const ushort_t* pb = ks ? pB1 : pB0;
      short8v af[4], bfv[4];
      #pragma unroll
      for (int i = 0; i < 4; ++i) af[i]  = *(const short8v*)(pa + i*1024);
      #pragma unroll
      for (int j = 0; j < 4; ++j) bfv[j] = *(const short8v*)(pb + j*1024);
      #pragma unroll
      for (int i = 0; i < 4; ++i)
        #pragma unroll
        for (int j = 0; j < 4; ++j)
          acc[i][j] = __builtin_amdgcn_mfma_f32_16x16x32_bf16(af[i], bfv[j], acc[i][j], 0, 0, 0);
    }
    __builtin_amdgcn_s_setprio(0);
    BARR();      // all waves' LDS reads of tile kt retired
    if (kt < 15) {
      stageS(bG, (kt+1)*64, lds + 8192, t);   // B(kt+1): overwrite safe post-barrier
      VM4();     // 8 A-loads (older) + 4 B-loads: drains exactly A(kt+1)
      #pragma unroll
      for (int it = 0; it < 4; ++it) {
        Aw[it].x = pk2(La[it][0].x, La[it][0].y);
        Aw[it].y = pk2(La[it][0].z, La[it][0].w);
        Aw[it].z = pk2(La[it][1].x, La[it][1].y);
        Aw[it].w = pk2(La[it][1].z, La[it][1].w);
      }
    }
  }

  // epilogue: partial score = sum_e tanh(acc + c) * wd[e]; spart[p][m]
  int p = n_blk*2 + we;
  #pragma unroll
  for (int i = 0; i < 4; ++i) {
    int mbase = m0 + wm*64 + i*16 + lk*4;
    f32x4 ps;
    #pragma unroll
    for (int r = 0; r < 4; ++r) {
      int m = mbase + r;
      int bb = (int)((unsigned)m / 196u);
      float partial = 0.f;
      #pragma unroll
      for (int j = 0; j < 4; ++j) {
        int ee = we*64 + j*16 + lrow;
        float v = acc[i][j][r] + c_lds[(bb - bb0)*128 + ee];
        float ex = __expf(2.f*v);
        partial += (1.f - 2.f/(ex + 1.f)) * wd[e0 + ee];
      }
      partial += __shfl_xor(partial, 1);
      partial += __shfl_xor(partial, 2);
      partial += __shfl_xor(partial, 4);
      partial += __shfl_xor(partial, 8);
      ps[r] = partial;
    }
    if (lrow == 0) *(f32x4*)(spart + (size_t)p*25088 + mbase) = ps;
  }
}

// ---------------- finalize: softmax over L, weighted sum of fp32 att (grid 512) ----------------
__global__ __launch_bounds__(256) void finalize_kernel(const float* __restrict__ att,
                                                       const float* __restrict__ spart,
                                                       float* __restrict__ out) {
  int b  = blockIdx.x >> 2;
  int dq = blockIdx.x & 3;
  int t  = threadIdx.x;
  __shared__ float wls[L_];
  __shared__ float red[8];

  float s = -1e30f;
  if (t < L_) {
    int m = b*L_ + t;
    float sum = 0.f;
    #pragma unroll
    for (int p = 0; p < 16; ++p) sum += spart[p*25088 + m];
    s = sum;                       // b_d2d omitted: softmax shift-invariant
  }
  float mx = s;
  #pragma unroll
  for (int off = 1; off < 64; off <<= 1) mx = fmaxf(mx, __shfl_xor(mx, off));
  if ((t & 63) == 0) red[t >> 6] = mx;
  __syncthreads();
  mx = fmaxf(fmaxf(red[0], red[1]), fmaxf(red[2], red[3]));
  float pr = (t < L_) ? __expf(s - mx) : 0.f;
  float ssum = pr;
  #pragma unroll
  for (int off = 1; off < 64; off <<= 1) ssum += __shfl_xor(ssum, off);
  if ((t & 63) == 0) red[4 + (t >> 6)] = ssum;
  __syncthreads();
  float tot = red[4] + red[5] + red[6] + red[7];
  if (t < L_) wls[t] = pr / tot;
  __syncthreads();

  if (t < 128) {
    int d = dq*256 + t*2;
    const float* abase = att + (size_t)b*L_*D_ + d;
    float a0 = 0.f, a1 = 0.f;
    #pragma unroll 4
    for (int l = 0; l < L_; ++l) {
      float wv = wls[l];
      float2 av = *(const float2*)(abase + (size_t)l*D_);
      a0 += wv*av.x; a1 += wv*av.y;
    }
    float2 o; o.x = a0; o.y = a1;
    *(float2*)(out + (size_t)b*D_ + d) = o;
  }
}

extern "C" void kernel_launch(void* const* d_in, const int* in_sizes, int n_in,
                              void* d_out, int out_size, void* d_ws, size_t ws_size,
                              hipStream_t stream) {
  (void)in_sizes; (void)n_in; (void)out_size; (void)ws_size;
  const float* x   = (const float*)d_in[0];
  const float* att = (const float*)d_in[1];
  const float* h   = (const float*)d_in[2];
  const float* Wa  = (const float*)d_in[3];
  const float* ba  = (const float*)d_in[4];
  const float* Wh  = (const float*)d_in[5];
  const float* bh  = (const float*)d_in[6];
  const float* Wi  = (const float*)d_in[7];
  const float* bi  = (const float*)d_in[8];
  const float* wd  = (const float*)d_in[9];
  // d_in[10] = b_d2d: softmax shift-invariant, unused

  char* ws = (char*)d_ws;
  ushort_t* W_bf   = (ushort_t*)(ws + OFF_WBF);
  ushort_t* A2     = (ushort_t*)(ws + OFF_A2);
  ushort_t* W2     = (ushort_t*)(ws + OFF_W2);
  float*    spart  = (float*)(ws + OFF_SPART);
  float*    cpart  = (float*)(ws + OFF_CPART);
  float*    out    = (float*)d_out;

  hipLaunchKernelGGL(convert_kernel, dim3(1024), dim3(256), 0, stream,
                     Wa, x, h, Wi, Wh, W_bf, A2, W2);
  hipLaunchKernelGGL(gemm_c_kernel, dim3(32), dim3(256), 0, stream,
                     A2, W2, cpart);
  hipLaunchKernelGGL(gemm_score_kernel, dim3(1568), dim3(256), 0, stream,
                     att, W_bf, cpart, ba, bh, bi, wd, spart);
  hipLaunchKernelGGL(finalize_kernel, dim3(512), dim3(256), 0, stream,
                     att, spart, out);
}

// Round 11
// 127.274 us; speedup vs baseline: 1.1741x; 1.0521x over previous
//
#include <hip/hip_runtime.h>
#include <hip/hip_bf16.h>

#define B_ 128
#define L_ 196
#define D_ 1024

typedef __attribute__((ext_vector_type(8))) short short8v;
typedef __attribute__((ext_vector_type(4))) float f32x4;
typedef unsigned short ushort_t;

// d_ws layout (bytes). Max footprint 60,293,120 (proven size).
#define OFF_ATTBF   0UL          // 25088*1024*2 = 51,380,224
#define OFF_WBF     51380224UL   // 1024*1024*2  =  2,097,152
#define OFF_A2      53477376UL   // 128*2048*2   =    524,288   [x|h] bf16
#define OFF_W2      54001664UL   // 1024*2048*2  =  4,194,304   [Wi|Wh] bf16
#define OFF_SPART   53477376UL   // 16*25088*4   =  1,605,632   (aliases A2/W2: dead before score)
#define OFF_CPART   58195968UL   // 4*128*1024*4 =  2,097,152   c partials

__device__ inline unsigned short f2bf(float f) {
  unsigned int u = __float_as_uint(f);
  unsigned int r = (u + 0x7fffu + ((u >> 16) & 1u)) >> 16;
  return (unsigned short)r;
}

// ---------------- convert: fp32 -> bf16 staging buffers (r3-proven) ----------------
__global__ void convert_kernel(const float* __restrict__ att, const float* __restrict__ Wa,
                               const float* __restrict__ x,   const float* __restrict__ h,
                               const float* __restrict__ Wi,  const float* __restrict__ Wh,
                               ushort_t* __restrict__ att_bf, ushort_t* __restrict__ W_bf,
                               ushort_t* __restrict__ A2,     ushort_t* __restrict__ W2) {
  const int n0 = (B_*L_*D_)/4;
  const int n1 = (D_*D_)/4;
  const int n2 = (B_*D_)/4;
  const int total = n0 + n1 + 2*n2 + 2*n1;
  for (int idx = blockIdx.x*blockDim.x + threadIdx.x; idx < total;
       idx += gridDim.x*blockDim.x) {
    const float4* src; ushort_t* dst;
    int i = idx;
    if (i < n0)               { src = (const float4*)att + i; dst = att_bf + (size_t)i*4; }
    else if ((i -= n0) < n1)  { src = (const float4*)Wa  + i; dst = W_bf  + (size_t)i*4; }
    else if ((i -= n1) < n2)  { int b = i>>8, k4 = i&255; src = (const float4*)x  + i; dst = A2 + b*2048 + k4*4; }
    else if ((i -= n2) < n2)  { int b = i>>8, k4 = i&255; src = (const float4*)h  + i; dst = A2 + b*2048 + 1024 + k4*4; }
    else if ((i -= n2) < n1)  { int e = i>>8, k4 = i&255; src = (const float4*)Wi + i; dst = W2 + e*2048 + k4*4; }
    else { i -= n1;             int e = i>>8, k4 = i&255; src = (const float4*)Wh + i; dst = W2 + e*2048 + 1024 + k4*4; }
    float4 v = *src;
    ushort4 o; o.x = f2bf(v.x); o.y = f2bf(v.y); o.z = f2bf(v.z); o.w = f2bf(v.w);
    *(ushort4*)dst = o;
  }
}

// ---------------- c-matrix GEMM, split-K x4 AND e-split x16 (grid 64) ----------------
// A-tile [128][64] staging (16KB, 4 gload/thread) — r3-proven formula.
__device__ inline void stage_tileA(const ushort_t* __restrict__ g, int Kld, int k0,
                                   ushort_t* ldst, int t) {
  #pragma unroll
  for (int it = 0; it < 4; ++it) {
    int linear = it*4096 + t*16;
    int r = linear >> 7;
    int c = (t & 7) ^ (r & 7);
    const ushort_t* src = g + (size_t)r*Kld + k0 + c*8;
    ushort_t* dst = ldst + ((it*4096 + ((t & 192) << 4)) >> 1);
    __builtin_amdgcn_global_load_lds((const __attribute__((address_space(1))) void*)src,
                                     (__attribute__((address_space(3))) void*)dst,
                                     16, 0, 0);
  }
}
// B-tile [64][64] staging (8KB, 2 gload/thread) — same swizzle, 64 rows.
__device__ inline void stage_tileB(const ushort_t* __restrict__ g, int row0, int Kld, int k0,
                                   ushort_t* ldst, int t) {
  #pragma unroll
  for (int it = 0; it < 2; ++it) {
    int linear = it*4096 + t*16;
    int r = linear >> 7;
    int c = (t & 7) ^ (r & 7);
    const ushort_t* src = g + (size_t)(row0 + r)*Kld + k0 + c*8;
    ushort_t* dst = ldst + ((it*4096 + ((t & 192) << 4)) >> 1);
    __builtin_amdgcn_global_load_lds((const __attribute__((address_space(1))) void*)src,
                                     (__attribute__((address_space(3))) void*)dst,
                                     16, 0, 0);
  }
}

__device__ inline short8v ldfrag(const ushort_t* tile, int row, int c) {
  int phys = c ^ (row & 7);
  return *(const short8v*)(tile + row*64 + phys*8);
}

__global__ __launch_bounds__(256) void gemm_c_kernel(
    const ushort_t* __restrict__ Amat, const ushort_t* __restrict__ Bmat,
    float* __restrict__ cpart) {
  __shared__ ushort_t lds[24576];   // 48KB: A0[0,8192) B0[8192,12288) A1[12288,20480) B1[20480,24576)
  int bid = blockIdx.x;
  int e0 = (bid & 15)*64;
  int kc = bid >> 4;               // 0..3, K-chunk of 512
  int kbeg = kc*512;
  const int Kld = 2048;
  int t = threadIdx.x, lane = t & 63, w = t >> 6;
  int wm = w >> 1, we = w & 1;
  int lrow = lane & 15;
  int lk = lane >> 4;

  f32x4 acc[4][2];
  #pragma unroll
  for (int i = 0; i < 4; ++i)
    #pragma unroll
    for (int j = 0; j < 2; ++j) acc[i][j] = (f32x4){0.f, 0.f, 0.f, 0.f};

  stage_tileA(Amat, Kld, kbeg, lds, t);
  stage_tileB(Bmat, e0, Kld, kbeg, lds + 8192, t);
  __syncthreads();

  const int nk = 8;                // 512 / 64
  for (int kt = 0; kt < nk; ++kt) {
    int cur = kt & 1;
    if (kt + 1 < nk) {
      stage_tileA(Amat, Kld, kbeg + ((kt+1) << 6), lds + (cur^1)*12288, t);
      stage_tileB(Bmat, e0, Kld, kbeg + ((kt+1) << 6), lds + (cur^1)*12288 + 8192, t);
    }
    const ushort_t* At = lds + cur*12288;
    const ushort_t* Bt = At + 8192;
    #pragma unroll
    for (int hh = 0; hh < 2; ++hh) {
      short8v af[4], bfv[2];
      #pragma unroll
      for (int i = 0; i < 4; ++i) af[i]  = ldfrag(At, wm*64 + i*16 + lrow, hh*4 + lk);
      #pragma unroll
      for (int j = 0; j < 2; ++j) bfv[j] = ldfrag(Bt, we*32 + j*16 + lrow, hh*4 + lk);
      #pragma unroll
      for (int i = 0; i < 4; ++i)
        #pragma unroll
        for (int j = 0; j < 2; ++j)
          acc[i][j] = __builtin_amdgcn_mfma_f32_16x16x32_bf16(af[i], bfv[j], acc[i][j], 0, 0, 0);
    }
    __syncthreads();
  }

  float* outc = cpart + (size_t)kc*131072;   // [128][1024] raw partial (no bias)
  #pragma unroll
  for (int i = 0; i < 4; ++i) {
    int m = wm*64 + i*16 + lk*4;
    #pragma unroll
    for (int j = 0; j < 2; ++j) {
      int e = e0 + we*32 + j*16 + lrow;
      #pragma unroll
      for (int r = 0; r < 4; ++r)
        outc[(m + r)*1024 + e] = acc[i][j][r];
    }
  }
}

// ---------------- 128x128 score GEMM: r7-proven (single-buffer, cross-block overlap) ----------------
#define BARR()  __builtin_amdgcn_s_barrier()
#define VM0()   asm volatile("s_waitcnt vmcnt(0)" ::: "memory")

// stage one 128x64 bf16 tile (16KB): 4 x global_load_lds(16B)/thread (r7-proven).
__device__ inline void stageS(const ushort_t* __restrict__ g, int k0, ushort_t* ldsbase, int t) {
  #pragma unroll
  for (int it = 0; it < 4; ++it) {
    int linear = it*4096 + t*16;
    int r = linear >> 7;
    int c = ((linear >> 4) & 7) ^ (r & 7);
    const ushort_t* src = g + (size_t)r*1024 + k0 + c*8;
    ushort_t* dst = ldsbase + ((it*4096 + ((t & 192) << 4)) >> 1);
    __builtin_amdgcn_global_load_lds((const __attribute__((address_space(1))) void*)src,
                                     (__attribute__((address_space(3))) void*)dst,
                                     16, 0, 0);
  }
}

__global__ __launch_bounds__(256) void gemm_score_kernel(
    const ushort_t* __restrict__ Amat, const ushort_t* __restrict__ Bmat,
    const float* __restrict__ cpart,
    const float* __restrict__ ba, const float* __restrict__ bh, const float* __restrict__ bi,
    const float* __restrict__ wd,
    float* __restrict__ spart) {
  __shared__ ushort_t lds[16384];   // 32 KB: A[128][64]@0, B[128][64]@8192 (elems)
  __shared__ float c_lds[256];      // [2][128]: c+biases for this block's (bb,e) range
  int bid = blockIdx.x;
  int swz = (bid & 7)*196 + (bid >> 3);    // 1568 % 8 == 0 -> bijective XCD swizzle
  int m_blk = swz >> 3, n_blk = swz & 7;
  int m0 = m_blk*128, e0 = n_blk*128;
  int t = (int)threadIdx.x, lane = t & 63, w = t >> 6;
  int wm = w >> 1, we = w & 1;
  int lrow = lane & 15, lk = lane >> 4;

  // c_lds = biases + sum of 4 K-partials
  int bb0 = m0 / 196;
  {
    int bb = bb0 + (t >> 7);
    int e  = e0 + (t & 127);
    float v = ba[e] + bh[e] + bi[e];
    if (bb < 128) {
      v += cpart[bb*1024 + e] + cpart[131072 + bb*1024 + e]
         + cpart[262144 + bb*1024 + e] + cpart[393216 + bb*1024 + e];
    }
    c_lds[t] = v;
  }

  const ushort_t* aG = Amat + (size_t)m0*1024;
  const ushort_t* bG = Bmat + (size_t)e0*1024;

  // loop-invariant ds_read base pointers (row&7 == lrow&7 for all frag rows)
  int lrow7 = lrow & 7;
  const ushort_t* pA0 = lds + (wm*64 + lrow)*64 + ((lk)     ^ lrow7)*8;
  const ushort_t* pA1 = lds + (wm*64 + lrow)*64 + (((4+lk)) ^ lrow7)*8;
  const ushort_t* pB0 = lds + 8192 + (we*64 + lrow)*64 + ((lk)     ^ lrow7)*8;
  const ushort_t* pB1 = lds + 8192 + (we*64 + lrow)*64 + (((4+lk)) ^ lrow7)*8;

  f32x4 acc[4][4];
  #pragma unroll
  for (int i = 0; i < 4; ++i)
    #pragma unroll
    for (int j = 0; j < 4; ++j) acc[i][j] = (f32x4){0.f, 0.f, 0.f, 0.f};

  // prologue: stage K-tile 0 (8 loads/thread outstanding)
  stageS(aG, 0, lds, t);
  stageS(bG, 0, lds + 8192, t);

  for (int kt = 0; kt < 16; ++kt) {
    VM0();      // own 8 staged loads landed
    BARR();     // all waves' loads landed -> tile kt complete
    __builtin_amdgcn_s_setprio(1);
    #pragma unroll
    for (int ks = 0; ks < 2; ++ks) {
      const ushort_t* pa = ks ? pA1 : pA0;
      const ushort_t* pb = ks ? pB1 : pB0;
      short8v af[4], bfv[4];
      #pragma unroll
      for (int i = 0; i < 4; ++i) af[i]  = *(const short8v*)(pa + i*1024);
      #pragma unroll
      for (int j = 0; j < 4; ++j) bfv[j] = *(const short8v*)(pb + j*1024);
      #pragma unroll
      for (int i = 0; i < 4; ++i)
        #pragma unroll
        for (int j = 0; j < 4; ++j)
          acc[i][j] = __builtin_amdgcn_mfma_f32_16x16x32_bf16(af[i], bfv[j], acc[i][j], 0, 0, 0);
    }
    __builtin_amdgcn_s_setprio(0);
    BARR();     // in-order issue: reaching here => all this wave's ds_reads retired
    if (kt < 15) {
      stageS(aG, (kt+1)*64, lds, t);         // overwrite is safe post-barrier
      stageS(bG, (kt+1)*64, lds + 8192, t);
    }
  }

  // epilogue: partial score = sum_e tanh(acc + c) * wd[e]; spart[p][m], float4 stores
  int p = n_blk*2 + we;
  #pragma unroll
  for (int i = 0; i < 4; ++i) {
    int mbase = m0 + wm*64 + i*16 + lk*4;
    f32x4 ps;
    #pragma unroll
    for (int r = 0; r < 4; ++r) {
      int m = mbase + r;
      int bb = (int)((unsigned)m / 196u);
      float partial = 0.f;
      #pragma unroll
      for (int j = 0; j < 4; ++j) {
        int ee = we*64 + j*16 + lrow;
        float v = acc[i][j][r] + c_lds[(bb - bb0)*128 + ee];
        float ex = __expf(2.f*v);
        partial += (1.f - 2.f/(ex + 1.f)) * wd[e0 + ee];
      }
      partial += __shfl_xor(partial, 1);
      partial += __shfl_xor(partial, 2);
      partial += __shfl_xor(partial, 4);
      partial += __shfl_xor(partial, 8);
      ps[r] = partial;
    }
    if (lrow == 0) *(f32x4*)(spart + (size_t)p*25088 + mbase) = ps;
  }
}

// ---------------- finalize: softmax over L, weighted sum of bf16 att (r4-proven, grid 256) ----------------
__global__ __launch_bounds__(256) void finalize_kernel(const ushort_t* __restrict__ att_bf,
                                                       const float* __restrict__ spart,
                                                       float* __restrict__ out) {
  int b  = blockIdx.x >> 1;
  int dh = blockIdx.x & 1;
  int t  = threadIdx.x;
  __shared__ float wls[L_];
  __shared__ float red[8];

  float s = -1e30f;
  if (t < L_) {
    int m = b*L_ + t;
    float sum = 0.f;
    #pragma unroll
    for (int p = 0; p < 16; ++p) sum += spart[p*25088 + m];
    s = sum;                       // b_d2d omitted: softmax shift-invariant
  }
  float mx = s;
  #pragma unroll
  for (int off = 1; off < 64; off <<= 1) mx = fmaxf(mx, __shfl_xor(mx, off));
  if ((t & 63) == 0) red[t >> 6] = mx;
  __syncthreads();
  mx = fmaxf(fmaxf(red[0], red[1]), fmaxf(red[2], red[3]));
  float pr = (t < L_) ? __expf(s - mx) : 0.f;
  float ssum = pr;
  #pragma unroll
  for (int off = 1; off < 64; off <<= 1) ssum += __shfl_xor(ssum, off);
  if ((t & 63) == 0) red[4 + (t >> 6)] = ssum;
  __syncthreads();
  float tot = red[4] + red[5] + red[6] + red[7];
  if (t < L_) wls[t] = pr / tot;
  __syncthreads();

  int d = dh*512 + t*2;
  const ushort_t* abase = att_bf + (size_t)b*L_*D_ + d;
  float a0 = 0.f, a1 = 0.f;
  #pragma unroll 4
  for (int l = 0; l < L_; ++l) {
    float wv = wls[l];
    unsigned int v = *(const unsigned int*)(abase + (size_t)l*D_);
    float lo = __uint_as_float(v << 16);
    float hi = __uint_as_float(v & 0xffff0000u);
    a0 += wv*lo; a1 += wv*hi;
  }
  float2 o; o.x = a0; o.y = a1;
  *(float2*)(out + (size_t)b*D_ + d) = o;
}

extern "C" void kernel_launch(void* const* d_in, const int* in_sizes, int n_in,
                              void* d_out, int out_size, void* d_ws, size_t ws_size,
                              hipStream_t stream) {
  (void)in_sizes; (void)n_in; (void)out_size; (void)ws_size;
  const float* x   = (const float*)d_in[0];
  const float* att = (const float*)d_in[1];
  const float* h   = (const float*)d_in[2];
  const float* Wa  = (const float*)d_in[3];
  const float* ba  = (const float*)d_in[4];
  const float* Wh  = (const float*)d_in[5];
  const float* bh  = (const float*)d_in[6];
  const float* Wi  = (const float*)d_in[7];
  const float* bi  = (const float*)d_in[8];
  const float* wd  = (const float*)d_in[9];
  // d_in[10] = b_d2d: softmax shift-invariant, unused

  char* ws = (char*)d_ws;
  ushort_t* att_bf = (ushort_t*)(ws + OFF_ATTBF);
  ushort_t* W_bf   = (ushort_t*)(ws + OFF_WBF);
  ushort_t* A2     = (ushort_t*)(ws + OFF_A2);
  ushort_t* W2     = (ushort_t*)(ws + OFF_W2);
  float*    cpart  = (float*)(ws + OFF_CPART);
  float*    spart  = (float*)(ws + OFF_SPART);
  float*    out    = (float*)d_out;

  hipLaunchKernelGGL(convert_kernel, dim3(2048), dim3(256), 0, stream,
                     att, Wa, x, h, Wi, Wh, att_bf, W_bf, A2, W2);
  hipLaunchKernelGGL(gemm_c_kernel, dim3(64), dim3(256), 0, stream,
                     A2, W2, cpart);
  hipLaunchKernelGGL(gemm_score_kernel, dim3(1568), dim3(256), 0, stream,
                     att_bf, W_bf, cpart, ba, bh, bi, wd, spart);
  hipLaunchKernelGGL(finalize_kernel, dim3(256), dim3(256), 0, stream,
                     att_bf, spart, out);
}